// Round 6
// baseline (91.210 us; speedup 1.0000x reference)
//
#include <hip/hip_runtime.h>

// Problem constants (fixed by setup_inputs / reference)
#define FH 2160
#define FW 3840
#define DH 1080
#define DW 1920
#define RAD 8
#define KS 17
#define INV_KS (1.0f / 17.0f)
#define EPS_GF 1e-3f
#define EPS_LOG 1e-6f
#define EPS_SCALE 1e-4f
#define A_COEF 0.7f

// Single-kernel tile geometry: 64x64 output px per block.
//   base tile   34x34  (32 core + bilinear +/-1 halo), origin (bh0,bw0)
//   a/b tile    50x50  (base + 2*RAD),                 origin (ah0,aw0)=(bh0-8,bw0-8)
//   D tile      66x66  (a/b + 2*RAD),                  origin (dh0,dw0)=(bh0-16,bw0-16)
#define DT 66
#define DTP 67
#define AT 50
#define ATP 51
#define BT 34
#define BTP 35

// Grid: 60 x 34 tiles = 2040 blocks (2040 % 8 == 0 -> simple XCD swizzle is bijective)
#define NTILES 2040
#define TPX 255             // tiles per XCD

__device__ __forceinline__ int refl(int p, int n) {
    // jnp.pad 'reflect' (no edge repeat). Max overhang here is 17 << n, one fold suffices.
    p = (p < 0) ? -p : p;
    return (p >= n) ? (2 * n - 2 - p) : p;
}

__device__ __forceinline__ float luma3(float r, float g, float b) {
    return 0.2126f * r + 0.7152f * g + 0.0722f * b;
}

// LDS regions (floats):
//   R0[5100]: inD 66x67=4422          -> phase3+: inA 50x51=2550 @0, inB @2550
//   R1[6600]: h1 66x50=3300 @0, h2 @3300
//             -> phase4+: hA 50x34=1700 @0, hB @3300, baseT 34x35=1190 @5000
//   R2[1156]: Dcore 34x34 (D at base-tile positions, survives R0 overwrite)
__global__ void __launch_bounds__(256, 3)
k_ltm(const float* __restrict__ x, float* __restrict__ out) {
    __shared__ float R0[5100];
    __shared__ float R1[6600];
    __shared__ float R2[1156];

    int bid = blockIdx.x;
    int swz = (bid & 7) * TPX + (bid >> 3);   // XCD-contiguous raster strips
    int bx = swz % 60, by = swz / 60;
    int ox0 = bx * 64, oy0 = by * 64;
    int bh0 = by * 32 - 1, bw0 = bx * 32 - 1;
    int dh0 = bh0 - 2 * RAD, dw0 = bw0 - 2 * RAD;
    int t = threadIdx.x;

    // ---- Phase 1: build D tile 66x66 from x (luma -> log2 -> 2x2 mean) ----
    // DOWN=0.5 align_corners=False bilinear == exact 2x2 mean of Y_log.
    float* inD = R0;
    for (int s = t; s < DT * DT; s += 256) {
        int li = s / DT, lj = s - li * DT;
        int gi = refl(dh0 + li, DH);
        int gj = refl(dw0 + lj, DW);
        const float* p0 = x + ((size_t)(2 * gi) * FW + (size_t)(2 * gj)) * 3;
        const float* p1 = p0 + (size_t)FW * 3;
        float2 a0 = *(const float2*)(p0);
        float2 a1 = *(const float2*)(p0 + 2);
        float2 a2 = *(const float2*)(p0 + 4);
        float2 b0 = *(const float2*)(p1);
        float2 b1 = *(const float2*)(p1 + 2);
        float2 b2 = *(const float2*)(p1 + 4);
        float y00 = luma3(a0.x, a0.y, a1.x);
        float y01 = luma3(a1.y, a2.x, a2.y);
        float y10 = luma3(b0.x, b0.y, b1.x);
        float y11 = luma3(b1.y, b2.x, b2.y);
        inD[li * DTP + lj] = 0.25f * (__log2f(fmaxf(y00, EPS_LOG)) +
                                      __log2f(fmaxf(y01, EPS_LOG)) +
                                      __log2f(fmaxf(y10, EPS_LOG)) +
                                      __log2f(fmaxf(y11, EPS_LOG)));
    }
    __syncthreads();

    // ---- Phase 2: hbox of I and I*I (66 rows x 50 cols); save Dcore ----
    float* h1 = R1;
    float* h2 = R1 + 3300;
    for (int idx = t; idx < DT * AT; idx += 256) {
        int r = idx / AT, c = idx - r * AT;
        const float* row = &inD[r * DTP + c];
        float s1 = 0.f, s2 = 0.f;
#pragma unroll
        for (int k = 0; k < KS; ++k) { float v = row[k]; s1 += v; s2 += v * v; }
        h1[idx] = s1 * INV_KS;
        h2[idx] = s2 * INV_KS;
    }
    for (int idx = t; idx < BT * BT; idx += 256) {
        int r = idx / BT, c = idx - r * BT;
        R2[idx] = inD[(r + 2 * RAD) * DTP + (c + 2 * RAD)];
    }
    __syncthreads();

    // ---- Phase 3: vbox -> a,b on 50x50 (overwrites inD region) ----
    float* inA = R0;
    float* inB = R0 + 2550;
    for (int idx = t; idx < AT * AT; idx += 256) {
        int r = idx / AT, c = idx - r * AT;
        float s1 = 0.f, s2 = 0.f;
#pragma unroll
        for (int k = 0; k < KS; ++k) {
            s1 += h1[(r + k) * AT + c];
            s2 += h2[(r + k) * AT + c];
        }
        float mI = s1 * INV_KS, mII = s2 * INV_KS;
        float var = mII - mI * mI;
        float av = var / (var + EPS_GF);
        inA[r * ATP + c] = av;
        inB[r * ATP + c] = mI - av * mI;
    }
    __syncthreads();

    // ---- Phase 4: hbox2 of a,b (50 rows x 34 cols; overwrites h1/h2) ----
    float* hA = R1;
    float* hB = R1 + 3300;
    for (int idx = t; idx < AT * BT; idx += 256) {
        int r = idx / BT, c = idx - r * BT;
        const float* ra = &inA[r * ATP + c];
        const float* rb = &inB[r * ATP + c];
        float s1 = 0.f, s2 = 0.f;
#pragma unroll
        for (int k = 0; k < KS; ++k) { s1 += ra[k]; s2 += rb[k]; }
        hA[r * BT + c] = s1 * INV_KS;
        hB[r * BT + c] = s2 * INV_KS;
    }
    __syncthreads();

    // ---- Phase 5: vbox2 -> base = mean_a * D + mean_b on 34x34 ----
    float* baseT = R1 + 5000;
    for (int idx = t; idx < BT * BT; idx += 256) {
        int r = idx / BT, c = idx - r * BT;
        float s1 = 0.f, s2 = 0.f;
#pragma unroll
        for (int k = 0; k < KS; ++k) {
            s1 += hA[(r + k) * BT + c];
            s2 += hB[(r + k) * BT + c];
        }
        baseT[r * BTP + c] = (s1 * INV_KS) * R2[idx] + s2 * INV_KS;
    }
    __syncthreads();

    // ---- Phase 6: upsample base + tonemap + scale + clip (64 rows x 16 quads) ----
    for (int q = t; q < 64 * 16; q += 256) {
        int qi = q >> 4, qj = q & 15;
        int oy = oy0 + qi;
        if (oy < FH) {
            float ys = fminf(fmaxf((oy + 0.5f) * 0.5f - 0.5f, 0.f), (float)(DH - 1));
            int y0 = (int)ys;
            int y1 = min(y0 + 1, DH - 1);
            float wy = ys - (float)y0;
            const float* br0 = &baseT[(y0 - bh0) * BTP];
            const float* br1 = &baseT[(y1 - bh0) * BTP];

            size_t off = ((size_t)oy * FW + (size_t)(ox0 + 4 * qj)) * 3;
            const float4* xin = (const float4*)(x + off);
            float4 v0 = xin[0], v1 = xin[1], v2 = xin[2];
            float px[12] = {v0.x, v0.y, v0.z, v0.w, v1.x, v1.y, v1.z, v1.w,
                            v2.x, v2.y, v2.z, v2.w};
            float po[12];
#pragma unroll
            for (int p = 0; p < 4; ++p) {
                int ox = ox0 + 4 * qj + p;
                float xs = fminf(fmaxf((ox + 0.5f) * 0.5f - 0.5f, 0.f), (float)(DW - 1));
                int x0 = (int)xs;
                int x1 = min(x0 + 1, DW - 1);
                float wx = xs - (float)x0;
                int c0 = x0 - bw0, c1 = x1 - bw0;
                float top = br0[c0] * (1.f - wx) + br0[c1] * wx;
                float bot = br1[c0] * (1.f - wx) + br1[c1] * wx;
                float Yb = top * (1.f - wy) + bot * wy;

                float cr = px[3 * p], cg = px[3 * p + 1], cb = px[3 * p + 2];
                float Y = luma3(cr, cg, cb);
                float Ylog = __log2f(fmaxf(Y, EPS_LOG));
                float Yout = exp2f(A_COEF * Yb + (Ylog - Yb));
                float sc = Yout / (Y + EPS_SCALE);
                po[3 * p + 0] = fminf(fmaxf(cr * sc, 0.f), 1.f);
                po[3 * p + 1] = fminf(fmaxf(cg * sc, 0.f), 1.f);
                po[3 * p + 2] = fminf(fmaxf(cb * sc, 0.f), 1.f);
            }
            float4* op = (float4*)(out + off);
            op[0] = make_float4(po[0], po[1], po[2], po[3]);
            op[1] = make_float4(po[4], po[5], po[6], po[7]);
            op[2] = make_float4(po[8], po[9], po[10], po[11]);
        }
    }
}

extern "C" void kernel_launch(void* const* d_in, const int* in_sizes, int n_in,
                              void* d_out, int out_size, void* d_ws, size_t ws_size,
                              hipStream_t stream) {
    const float* x = (const float*)d_in[0];
    float* out = (float*)d_out;
    k_ltm<<<dim3(NTILES), dim3(256), 0, stream>>>(x, out);
}

// Round 7
// 74.703 us; speedup vs baseline: 1.2210x; 1.2210x over previous
//
#include <hip/hip_runtime.h>

// Problem constants (fixed by setup_inputs / reference)
#define FH 2160
#define FW 3840
#define DH 1080
#define DW 1920
#define RAD 8
#define KS 17
#define INV_KS (1.0f / 17.0f)
#define EPS_GF 1e-3f
#define EPS_LOG 1e-6f
#define EPS_SCALE 1e-4f
#define A_COEF 0.7f

// K1 geometry: 32x32 core of D/a/b per block, D halo tile 48x48 built from x 96x96
#define TS 32
#define IT 48               // TS + 2*RAD
#define ITP 49              // padded stride

// K2 geometry: 64x64 output px per block; base tile 34x34 (32 + bilinear +/-1 halo);
// a/b tile 50x50 (34 + 2*RAD)
#define AT 50
#define ATP 51
#define BT 34
#define BTP 35

// Grid: 60 x 34 tiles = 2040 blocks (2040 % 8 == 0 -> simple XCD swizzle is bijective)
#define NTILES 2040
#define TPX 255             // tiles per XCD

__device__ __forceinline__ int refl(int p, int n) {
    // jnp.pad 'reflect' (no edge repeat). Max overhang 17 << n, one fold suffices.
    p = (p < 0) ? -p : p;
    return (p >= n) ? (2 * n - 2 - p) : p;
}

__device__ __forceinline__ float luma3(float r, float g, float b) {
    return 0.2126f * r + 0.7152f * g + 0.0722f * b;
}

// ---- K1: x -> D, {a,b}  (downsample fused with GF stage 1) ----
__global__ void __launch_bounds__(256)
k_gf_front(const float* __restrict__ x, float* __restrict__ Dg,
           float2* __restrict__ ABg) {
    __shared__ float inD[IT * ITP];   // 48x49 = 9.4 KB
    __shared__ float2 hh[IT * TS];    // 48x32 f2 = 12.3 KB  (.x = mean_I taps, .y = mean_II taps)
    int bid = blockIdx.x;
    int swz = (bid & 7) * TPX + (bid >> 3);   // XCD-contiguous raster strips
    int bx = swz % 60, by = swz / 60;
    int tx0 = bx * TS, ty0 = by * TS;
    int t = threadIdx.x;

    // Phase 1: D halo tile from x (luma -> log2 -> 2x2 mean).
    // DOWN=0.5 align_corners=False bilinear == exact 2x2 mean; sum of 4 log2 == log2 of product.
    for (int s = t; s < IT * IT; s += 256) {          // 2304 = 9*256 exact
        int li = s / IT, lj = s - li * IT;
        int gi = refl(ty0 - RAD + li, DH);
        int gj = refl(tx0 - RAD + lj, DW);
        const float* p0 = x + ((size_t)(2 * gi) * FW + (size_t)(2 * gj)) * 3;
        const float* p1 = p0 + (size_t)FW * 3;
        float2 a0 = *(const float2*)(p0);
        float2 a1 = *(const float2*)(p0 + 2);
        float2 a2 = *(const float2*)(p0 + 4);
        float2 b0 = *(const float2*)(p1);
        float2 b1 = *(const float2*)(p1 + 2);
        float2 b2 = *(const float2*)(p1 + 4);
        float y00 = fmaxf(luma3(a0.x, a0.y, a1.x), EPS_LOG);
        float y01 = fmaxf(luma3(a1.y, a2.x, a2.y), EPS_LOG);
        float y10 = fmaxf(luma3(b0.x, b0.y, b1.x), EPS_LOG);
        float y11 = fmaxf(luma3(b1.y, b2.x, b2.y), EPS_LOG);
        inD[li * ITP + lj] = 0.25f * __log2f((y00 * y01) * (y10 * y11));
    }
    __syncthreads();

    // Phase 2: hbox of I and I*I
    for (int idx = t; idx < IT * TS; idx += 256) {
        int r = idx >> 5, c = idx & 31;
        const float* row = &inD[r * ITP + c];
        float s1 = 0.f, s2 = 0.f;
#pragma unroll
        for (int k = 0; k < KS; ++k) { float v = row[k]; s1 += v; s2 += v * v; }
        hh[idx] = make_float2(s1 * INV_KS, s2 * INV_KS);
    }
    __syncthreads();

    // Phase 3: vbox -> a,b ; also write D core
    for (int idx = t; idx < TS * TS; idx += 256) {
        int r = idx >> 5, c = idx & 31;
        int gi = ty0 + r;
        if (gi < DH) {
            float s1 = 0.f, s2 = 0.f;
#pragma unroll
            for (int k = 0; k < KS; ++k) {
                float2 h = hh[(r + k) * TS + c];
                s1 += h.x;
                s2 += h.y;
            }
            float mI = s1 * INV_KS, mII = s2 * INV_KS;
            float var = mII - mI * mI;
            float av = var / (var + EPS_GF);
            size_t g = (size_t)gi * DW + tx0 + c;
            ABg[g] = make_float2(av, mI - av * mI);
            Dg[g] = inD[(r + RAD) * ITP + c + RAD];
        }
    }
}

// ---- K2: {a,b},D,x -> out  (GF stage 2 fused with upsample + tonemap) ----
__global__ void __launch_bounds__(256)
k_gf_back(const float* __restrict__ x, const float2* __restrict__ ABg,
          const float* __restrict__ Dg, float* __restrict__ out) {
    __shared__ float2 inAB[AT * ATP];    // 50x51 f2 = 20.4 KB
    __shared__ float2 hAB[AT * BT];      // 50x34 f2 = 13.6 KB
    __shared__ float baseT[BT * BTP];    // 34x35 = 4.8 KB
    int bid = blockIdx.x;
    int swz = (bid & 7) * TPX + (bid >> 3);
    int bx = swz % 60, by = swz / 60;
    int ox0 = bx * 64, oy0 = by * 64;
    int bh0 = by * 32 - 1, bw0 = bx * 32 - 1;   // base tile origin (incl -1 bilinear halo)
    int ah0 = bh0 - RAD, aw0 = bw0 - RAD;       // a/b tile origin
    int t = threadIdx.x;

    for (int s = t; s < AT * AT; s += 256) {
        int li = s / AT, lj = s - li * AT;
        inAB[li * ATP + lj] = ABg[(size_t)refl(ah0 + li, DH) * DW + refl(aw0 + lj, DW)];
    }
    __syncthreads();

    for (int idx = t; idx < AT * BT; idx += 256) {
        int r = idx / BT, c = idx - r * BT;
        const float2* ra = &inAB[r * ATP + c];
        float s1 = 0.f, s2 = 0.f;
#pragma unroll
        for (int k = 0; k < KS; ++k) { float2 v = ra[k]; s1 += v.x; s2 += v.y; }
        hAB[r * BT + c] = make_float2(s1 * INV_KS, s2 * INV_KS);
    }
    __syncthreads();

    for (int idx = t; idx < BT * BT; idx += 256) {
        int r = idx / BT, c = idx - r * BT;
        float s1 = 0.f, s2 = 0.f;
#pragma unroll
        for (int k = 0; k < KS; ++k) {
            float2 v = hAB[(r + k) * BT + c];
            s1 += v.x;
            s2 += v.y;
        }
        size_t g = (size_t)refl(bh0 + r, DH) * DW + refl(bw0 + c, DW);
        baseT[r * BTP + c] = (s1 * INV_KS) * Dg[g] + s2 * INV_KS;
    }
    __syncthreads();

    // upsample base from LDS + tonemap + scale + clip; 64 rows x 16 quads of 4 px
    for (int q = t; q < 64 * 16; q += 256) {
        int qi = q >> 4, qj = q & 15;
        int oy = oy0 + qi;
        if (oy < FH) {
            float ys = fminf(fmaxf((oy + 0.5f) * 0.5f - 0.5f, 0.f), (float)(DH - 1));
            int y0 = (int)ys;
            int y1 = min(y0 + 1, DH - 1);
            float wy = ys - (float)y0;
            const float* br0 = &baseT[(y0 - bh0) * BTP];
            const float* br1 = &baseT[(y1 - bh0) * BTP];

            size_t off = ((size_t)oy * FW + (size_t)(ox0 + 4 * qj)) * 3;
            const float4* xin = (const float4*)(x + off);
            float4 v0 = xin[0], v1 = xin[1], v2 = xin[2];
            float px[12] = {v0.x, v0.y, v0.z, v0.w, v1.x, v1.y, v1.z, v1.w,
                            v2.x, v2.y, v2.z, v2.w};
            float po[12];
#pragma unroll
            for (int p = 0; p < 4; ++p) {
                int ox = ox0 + 4 * qj + p;
                float xs = fminf(fmaxf((ox + 0.5f) * 0.5f - 0.5f, 0.f), (float)(DW - 1));
                int x0 = (int)xs;
                int x1 = min(x0 + 1, DW - 1);
                float wx = xs - (float)x0;
                int c0 = x0 - bw0, c1 = x1 - bw0;
                float top = br0[c0] * (1.f - wx) + br0[c1] * wx;
                float bot = br1[c0] * (1.f - wx) + br1[c1] * wx;
                float Yb = top * (1.f - wy) + bot * wy;

                float cr = px[3 * p], cg = px[3 * p + 1], cb = px[3 * p + 2];
                float Y = luma3(cr, cg, cb);
                float Ylog = __log2f(fmaxf(Y, EPS_LOG));
                float Yout = exp2f(A_COEF * Yb + (Ylog - Yb));
                float sc = Yout / (Y + EPS_SCALE);
                po[3 * p + 0] = fminf(fmaxf(cr * sc, 0.f), 1.f);
                po[3 * p + 1] = fminf(fmaxf(cg * sc, 0.f), 1.f);
                po[3 * p + 2] = fminf(fmaxf(cb * sc, 0.f), 1.f);
            }
            float4* op = (float4*)(out + off);
            op[0] = make_float4(po[0], po[1], po[2], po[3]);
            op[1] = make_float4(po[4], po[5], po[6], po[7]);
            op[2] = make_float4(po[8], po[9], po[10], po[11]);
        }
    }
}

extern "C" void kernel_launch(void* const* d_in, const int* in_sizes, int n_in,
                              void* d_out, int out_size, void* d_ws, size_t ws_size,
                              hipStream_t stream) {
    const float* x = (const float*)d_in[0];
    float* out = (float*)d_out;
    float* ws = (float*)d_ws;
    const size_t DN = (size_t)DW * DH;  // 8.29 MB

    float* D = ws;                        // DN floats
    float2* AB = (float2*)(ws + DN);      // DN float2 (2*DN floats)

    k_gf_front<<<dim3(NTILES), dim3(256), 0, stream>>>(x, D, AB);
    k_gf_back <<<dim3(NTILES), dim3(256), 0, stream>>>(x, AB, D, out);
}

// Round 8
// 71.629 us; speedup vs baseline: 1.2734x; 1.0429x over previous
//
#include <hip/hip_runtime.h>

// Problem constants (fixed by setup_inputs / reference)
#define FH 2160
#define FW 3840
#define DH 1080
#define DW 1920
#define RAD 8
#define KS 17
#define INV_KS (1.0f / 17.0f)
#define EPS_GF 1e-3f
#define EPS_LOG 1e-6f
#define EPS_SCALE 1e-4f
#define A_COEF 0.7f

// K1 geometry: 32x32 core of D/a/b per block, D halo tile 48x48 built from x 96x96
#define TS 32
#define IT 48               // TS + 2*RAD
#define ITP 50              // EVEN padded stride (float2-aligned strip reads)

// K2 geometry: 64x64 output px per block; base tile 34x34 (32 + bilinear +/-1 halo);
// a/b tile 50x50 (34 + 2*RAD)
#define AT 50
#define ATP2 52             // even float2 stride, cols 50/51 = tail padding
#define BT 34
#define BTP 35
#define HROWS 52            // hAB rows incl. 2 pad rows for tail strips

// Grid: 60 x 34 tiles = 2040 blocks (2040 % 8 == 0 -> simple XCD swizzle is bijective)
#define NTILES 2040
#define TPX 255             // tiles per XCD

__device__ __forceinline__ int refl(int p, int n) {
    // jnp.pad 'reflect' (no edge repeat). Max overhang 17 << n, one fold suffices.
    p = (p < 0) ? -p : p;
    return (p >= n) ? (2 * n - 2 - p) : p;
}

__device__ __forceinline__ float luma3(float r, float g, float b) {
    return 0.2126f * r + 0.7152f * g + 0.0722f * b;
}

// ---- K1: x -> D, {a,b}  (downsample fused with GF stage 1) ----
__global__ void __launch_bounds__(256)
k_gf_front(const float* __restrict__ x, float* __restrict__ Dg,
           float2* __restrict__ ABg) {
    __shared__ float inD[IT * ITP];   // 48x50 = 9.6 KB
    __shared__ float2 hh[IT * TS];    // 48x32 f2 = 12.3 KB  (.x = I taps, .y = I*I taps)
    int bid = blockIdx.x;
    int swz = (bid & 7) * TPX + (bid >> 3);   // XCD-contiguous raster strips
    int bx = swz % 60, by = swz / 60;
    int tx0 = bx * TS, ty0 = by * TS;
    int t = threadIdx.x;

    // Phase 1: D halo tile from x (luma -> log2 -> 2x2 mean).
    // DOWN=0.5 align_corners=False bilinear == exact 2x2 mean; sum of 4 log2 == log2 of product.
    for (int s = t; s < IT * IT; s += 256) {
        int li = s / IT, lj = s - li * IT;
        int gi = refl(ty0 - RAD + li, DH);
        int gj = refl(tx0 - RAD + lj, DW);
        const float* p0 = x + ((size_t)(2 * gi) * FW + (size_t)(2 * gj)) * 3;
        const float* p1 = p0 + (size_t)FW * 3;
        float2 a0 = *(const float2*)(p0);
        float2 a1 = *(const float2*)(p0 + 2);
        float2 a2 = *(const float2*)(p0 + 4);
        float2 b0 = *(const float2*)(p1);
        float2 b1 = *(const float2*)(p1 + 2);
        float2 b2 = *(const float2*)(p1 + 4);
        float y00 = fmaxf(luma3(a0.x, a0.y, a1.x), EPS_LOG);
        float y01 = fmaxf(luma3(a1.y, a2.x, a2.y), EPS_LOG);
        float y10 = fmaxf(luma3(b0.x, b0.y, b1.x), EPS_LOG);
        float y11 = fmaxf(luma3(b1.y, b2.x, b2.y), EPS_LOG);
        inD[li * ITP + lj] = 0.25f * __log2f((y00 * y01) * (y10 * y11));
    }
    __syncthreads();

    // Phase 2: hbox of I and I*I, strip-4 sliding. tasks = 48 rows x 8 strips = 384
    for (int task = t; task < IT * 8; task += 256) {
        int r = task >> 3, c0 = (task & 7) * 4;
        const float* row = &inD[r * ITP + c0];
        const float2* row2 = (const float2*)row;   // (r*50 + c0) even -> 8B aligned
        float s1 = 0.f, s2 = 0.f;
#pragma unroll
        for (int k = 0; k < 8; ++k) {
            float2 p = row2[k];
            s1 += p.x + p.y;
            s2 += p.x * p.x + p.y * p.y;
        }
        float v16 = row[16];
        s1 += v16; s2 += v16 * v16;
        int base = r * TS + c0;
        hh[base] = make_float2(s1 * INV_KS, s2 * INV_KS);
#pragma unroll
        for (int cc = 1; cc < 4; ++cc) {
            float vo = row[cc - 1], vi = row[cc + 16];
            s1 += vi - vo;
            s2 += vi * vi - vo * vo;
            hh[base + cc] = make_float2(s1 * INV_KS, s2 * INV_KS);
        }
    }
    __syncthreads();

    // Phase 3: vbox strip-4 -> a,b ; also write D core. tasks = 8 rstrips x 32 cols = 256
    {
        int rs = t >> 5, c = t & 31;
        int r0 = rs * 4;
        float sx = 0.f, sy = 0.f;
#pragma unroll
        for (int k = 0; k < KS; ++k) {
            float2 h = hh[(r0 + k) * TS + c];
            sx += h.x; sy += h.y;
        }
#pragma unroll
        for (int rr = 0; rr < 4; ++rr) {
            int r = r0 + rr;
            if (rr > 0) {
                float2 hi = hh[(r + 16) * TS + c];
                float2 ho = hh[(r - 1) * TS + c];
                sx += hi.x - ho.x;
                sy += hi.y - ho.y;
            }
            int gi = ty0 + r;
            if (gi < DH) {
                float mI = sx * INV_KS, mII = sy * INV_KS;
                float var = mII - mI * mI;
                float av = var / (var + EPS_GF);
                size_t g = (size_t)gi * DW + tx0 + c;
                ABg[g] = make_float2(av, mI - av * mI);
                Dg[g] = inD[(r + RAD) * ITP + c + RAD];
            }
        }
    }
}

// ---- K2: {a,b},D,x -> out  (GF stage 2 fused with upsample + tonemap) ----
__global__ void __launch_bounds__(256)
k_gf_back(const float* __restrict__ x, const float2* __restrict__ ABg,
          const float* __restrict__ Dg, float* __restrict__ out) {
    __shared__ float2 inAB[AT * ATP2];    // 50x52 f2 = 20.8 KB (cols 50/51 pad)
    __shared__ float2 hAB[HROWS * BT];    // 52x34 f2 = 14.1 KB (rows 50/51 pad)
    __shared__ float baseT[BT * BTP];     // 34x35 = 4.8 KB
    int bid = blockIdx.x;
    int swz = (bid & 7) * TPX + (bid >> 3);
    int bx = swz % 60, by = swz / 60;
    int ox0 = bx * 64, oy0 = by * 64;
    int bh0 = by * 32 - 1, bw0 = bx * 32 - 1;   // base tile origin (incl -1 bilinear halo)
    int ah0 = bh0 - RAD, aw0 = bw0 - RAD;       // a/b tile origin
    int t = threadIdx.x;

    for (int s = t; s < AT * AT; s += 256) {
        int li = s / AT, lj = s - li * AT;
        inAB[li * ATP2 + lj] = ABg[(size_t)refl(ah0 + li, DH) * DW + refl(aw0 + lj, DW)];
    }
    __syncthreads();

    // hbox strip-4: tasks = 50 rows x 9 strips = 450. Tail strip (c0=32) slides into
    // in-row padding (cols 50/51, stale) -> pollutes only discarded outputs 34/35.
    for (int task = t; task < AT * 9; task += 256) {
        int r = task / 9, c0 = (task - r * 9) * 4;
        const float2* row = &inAB[r * ATP2 + c0];
        float s1 = 0.f, s2 = 0.f;
#pragma unroll
        for (int k = 0; k < KS; ++k) { float2 v = row[k]; s1 += v.x; s2 += v.y; }
        int base = r * BT + c0;
#pragma unroll
        for (int cc = 0; cc < 4; ++cc) {
            if (cc > 0) {
                float2 vi = row[cc + 16], vo = row[cc - 1];
                s1 += vi.x - vo.x;
                s2 += vi.y - vo.y;
            }
            if (c0 + cc < BT) hAB[base + cc] = make_float2(s1 * INV_KS, s2 * INV_KS);
        }
    }
    __syncthreads();

    // vbox strip-4: tasks = 9 rstrips x 34 cols = 306. Tail strip slides into pad rows
    // 50/51 (stale) -> pollutes only discarded outputs rows 34/35.
    for (int task = t; task < 9 * BT; task += 256) {
        int rs = task / BT, c = task - rs * BT;
        int r0 = rs * 4;
        float s1 = 0.f, s2 = 0.f;
#pragma unroll
        for (int k = 0; k < KS; ++k) {
            float2 v = hAB[(r0 + k) * BT + c];
            s1 += v.x; s2 += v.y;
        }
#pragma unroll
        for (int rr = 0; rr < 4; ++rr) {
            int r = r0 + rr;
            if (rr > 0) {
                float2 vi = hAB[(r + 16) * BT + c];
                float2 vo = hAB[(r - 1) * BT + c];
                s1 += vi.x - vo.x;
                s2 += vi.y - vo.y;
            }
            if (r < BT) {
                size_t g = (size_t)refl(bh0 + r, DH) * DW + refl(bw0 + c, DW);
                baseT[r * BTP + c] = (s1 * INV_KS) * Dg[g] + s2 * INV_KS;
            }
        }
    }
    __syncthreads();

    // upsample base from LDS + tonemap + scale + clip; 64 rows x 16 quads of 4 px
    for (int q = t; q < 64 * 16; q += 256) {
        int qi = q >> 4, qj = q & 15;
        int oy = oy0 + qi;
        if (oy < FH) {
            float ys = fminf(fmaxf((oy + 0.5f) * 0.5f - 0.5f, 0.f), (float)(DH - 1));
            int y0 = (int)ys;
            int y1 = min(y0 + 1, DH - 1);
            float wy = ys - (float)y0;
            const float* br0 = &baseT[(y0 - bh0) * BTP];
            const float* br1 = &baseT[(y1 - bh0) * BTP];

            size_t off = ((size_t)oy * FW + (size_t)(ox0 + 4 * qj)) * 3;
            const float4* xin = (const float4*)(x + off);
            float4 v0 = xin[0], v1 = xin[1], v2 = xin[2];
            float px[12] = {v0.x, v0.y, v0.z, v0.w, v1.x, v1.y, v1.z, v1.w,
                            v2.x, v2.y, v2.z, v2.w};
            float po[12];
#pragma unroll
            for (int p = 0; p < 4; ++p) {
                int ox = ox0 + 4 * qj + p;
                float xs = fminf(fmaxf((ox + 0.5f) * 0.5f - 0.5f, 0.f), (float)(DW - 1));
                int x0 = (int)xs;
                int x1 = min(x0 + 1, DW - 1);
                float wx = xs - (float)x0;
                int c0 = x0 - bw0, c1 = x1 - bw0;
                float top = br0[c0] * (1.f - wx) + br0[c1] * wx;
                float bot = br1[c0] * (1.f - wx) + br1[c1] * wx;
                float Yb = top * (1.f - wy) + bot * wy;

                float cr = px[3 * p], cg = px[3 * p + 1], cb = px[3 * p + 2];
                float Y = luma3(cr, cg, cb);
                float Ylog = __log2f(fmaxf(Y, EPS_LOG));
                float Yout = exp2f(A_COEF * Yb + (Ylog - Yb));
                float sc = Yout / (Y + EPS_SCALE);
                po[3 * p + 0] = fminf(fmaxf(cr * sc, 0.f), 1.f);
                po[3 * p + 1] = fminf(fmaxf(cg * sc, 0.f), 1.f);
                po[3 * p + 2] = fminf(fmaxf(cb * sc, 0.f), 1.f);
            }
            float4* op = (float4*)(out + off);
            op[0] = make_float4(po[0], po[1], po[2], po[3]);
            op[1] = make_float4(po[4], po[5], po[6], po[7]);
            op[2] = make_float4(po[8], po[9], po[10], po[11]);
        }
    }
}

extern "C" void kernel_launch(void* const* d_in, const int* in_sizes, int n_in,
                              void* d_out, int out_size, void* d_ws, size_t ws_size,
                              hipStream_t stream) {
    const float* x = (const float*)d_in[0];
    float* out = (float*)d_out;
    float* ws = (float*)d_ws;
    const size_t DN = (size_t)DW * DH;  // 8.29 MB

    float* D = ws;                        // DN floats
    float2* AB = (float2*)(ws + DN);      // DN float2

    k_gf_front<<<dim3(NTILES), dim3(256), 0, stream>>>(x, D, AB);
    k_gf_back <<<dim3(NTILES), dim3(256), 0, stream>>>(x, AB, D, out);
}